// Round 7
// baseline (391.128 us; speedup 1.0000x reference)
//
#include <hip/hip_runtime.h>
#include <cstdint>
#include <cstddef>

// S=4096, D=1024, H=16, DH=64, F=4096. fp32 in/out, bf16 MFMA compute.

typedef __attribute__((ext_vector_type(8))) __bf16 bf16x8;
typedef __attribute__((ext_vector_type(4))) float f32x4;
typedef __attribute__((ext_vector_type(2))) float f32x2;
typedef __attribute__((ext_vector_type(16))) float f32x16;
typedef __attribute__((ext_vector_type(4))) unsigned int u32x4;

__device__ inline unsigned short f2bf(float f) {
  unsigned int u = __float_as_uint(f);
  u += 0x7fffu + ((u >> 16) & 1u);   // round-to-nearest-even
  return (unsigned short)(u >> 16);
}

__device__ inline void gload_lds16(const unsigned short* g, unsigned short* l) {
  __builtin_amdgcn_global_load_lds(
      (const __attribute__((address_space(1))) void*)g,
      (__attribute__((address_space(3))) void*)l, 16, 0, 0);
}

// ---------------- fused preprocessing: 6 transposes + bias concat + LN1, ONE launch ----------------
// Blocks 0..11: concat bqkv. Blocks 12..4107: LN1 rows (independent of weights).
// Blocks 4108..: 32x32 transpose tiles for Wq,Wk,Wv,Wo (1024 each), W1 (4096), W2 (4096).
// Grid = 12 + 4096 + 12288 = 16396.
__global__ __launch_bounds__(256) void prep_all(
    const float* __restrict__ Wq, const float* __restrict__ Wk,
    const float* __restrict__ Wv, const float* __restrict__ Wo,
    const float* __restrict__ W1, const float* __restrict__ W2,
    const float* __restrict__ bq, const float* __restrict__ bk,
    const float* __restrict__ bv,
    const float* __restrict__ x, const float* __restrict__ g1,
    const float* __restrict__ be1, unsigned short* __restrict__ y1,
    unsigned short* __restrict__ WqkvT, unsigned short* __restrict__ WoT,
    unsigned short* __restrict__ W1T, unsigned short* __restrict__ W2T,
    float* __restrict__ bqkv) {
  int b = blockIdx.x;
  const int tid = threadIdx.x;
  if (b < 12) {  // bias concat: 3072 floats
    int i = b * 256 + tid;
    bqkv[i] = (i < 1024) ? bq[i] : (i < 2048 ? bk[i - 1024] : bv[i - 2048]);
    return;
  }
  b -= 12;
  if (b < 4096) {  // ---- LayerNorm row b -> y1 (bf16) ----
    const int row = b;
    const float4 v = ((const float4*)(x + (size_t)row * 1024))[tid];
    float s = v.x + v.y + v.z + v.w;
#pragma unroll
    for (int off = 1; off < 64; off <<= 1) s += __shfl_xor(s, off);
    __shared__ float red1[4], red2[4];
    int wave = tid >> 6;
    if ((tid & 63) == 0) red1[wave] = s;
    __syncthreads();
    float mu = (red1[0] + red1[1] + red1[2] + red1[3]) * (1.0f / 1024.0f);
    float dx = v.x - mu, dy = v.y - mu, dz = v.z - mu, dw = v.w - mu;
    float s2 = dx * dx + dy * dy + dz * dz + dw * dw;
#pragma unroll
    for (int off = 1; off < 64; off <<= 1) s2 += __shfl_xor(s2, off);
    if ((tid & 63) == 0) red2[wave] = s2;
    __syncthreads();
    float var = (red2[0] + red2[1] + red2[2] + red2[3]) * (1.0f / 1024.0f);
    float inv = rsqrtf(var + 1e-6f);
    int c = tid * 4;
    ushort4 o;
    o.x = f2bf(dx * inv * g1[c + 0] + be1[c + 0]);
    o.y = f2bf(dy * inv * g1[c + 1] + be1[c + 1]);
    o.z = f2bf(dz * inv * g1[c + 2] + be1[c + 2]);
    o.w = f2bf(dw * inv * g1[c + 3] + be1[c + 3]);
    ((ushort4*)(y1 + (size_t)row * 1024))[tid] = o;
    return;
  }
  b -= 4096;
  const float* in;
  unsigned short* out;
  int K, N, nbx;
  if (b < 4096) {               // Wq/Wk/Wv/Wo: 1024x1024 each, 1024 tiles each
    const int sel = b >> 10;
    in = (sel == 0) ? Wq : (sel == 1) ? Wk : (sel == 2) ? Wv : Wo;
    out = (sel == 3) ? WoT : WqkvT + (size_t)sel * 1024 * 1024;
    K = 1024; N = 1024; nbx = 32; b &= 1023;
  } else if (b < 8192) {        // W1: [1024][4096] -> W1T [4096][1024]
    b -= 4096; in = W1; out = W1T; K = 1024; N = 4096; nbx = 128;
  } else {                      // W2: [4096][1024] -> W2T [1024][4096]
    b -= 8192; in = W2; out = W2T; K = 4096; N = 1024; nbx = 32;
  }
  const int nb = (b % nbx) * 32, kb = (b / nbx) * 32;
  __shared__ float t[32][33];
  const int tx = tid & 31, ty = tid >> 5;  // 32 x 8
#pragma unroll
  for (int i = 0; i < 32; i += 8)
    t[ty + i][tx] = in[(size_t)(kb + ty + i) * N + nb + tx];
  __syncthreads();
#pragma unroll
  for (int i = 0; i < 32; i += 8)
    out[(size_t)(nb + ty + i) * K + kb + tx] = f2bf(t[tx][ty + i]);
}

// ---------------- LayerNorm row (D=1024), output bf16 (used for LN2) ----------------
__global__ __launch_bounds__(256) void ln_kernel(const float* __restrict__ x,
                                                 const float* __restrict__ gamma,
                                                 const float* __restrict__ beta,
                                                 unsigned short* __restrict__ y) {
  int row = blockIdx.x, tid = threadIdx.x;
  const float4 v = ((const float4*)(x + (size_t)row * 1024))[tid];
  float s = v.x + v.y + v.z + v.w;
#pragma unroll
  for (int off = 1; off < 64; off <<= 1) s += __shfl_xor(s, off);
  __shared__ float red1[4], red2[4];
  int wave = tid >> 6;
  if ((tid & 63) == 0) red1[wave] = s;
  __syncthreads();
  float mu = (red1[0] + red1[1] + red1[2] + red1[3]) * (1.0f / 1024.0f);
  float dx = v.x - mu, dy = v.y - mu, dz = v.z - mu, dw = v.w - mu;
  float s2 = dx * dx + dy * dy + dz * dz + dw * dw;
#pragma unroll
  for (int off = 1; off < 64; off <<= 1) s2 += __shfl_xor(s2, off);
  if ((tid & 63) == 0) red2[wave] = s2;
  __syncthreads();
  float var = (red2[0] + red2[1] + red2[2] + red2[3]) * (1.0f / 1024.0f);
  float inv = rsqrtf(var + 1e-6f);
  int c = tid * 4;
  ushort4 o;
  o.x = f2bf(dx * inv * gamma[c + 0] + beta[c + 0]);
  o.y = f2bf(dy * inv * gamma[c + 1] + beta[c + 1]);
  o.z = f2bf(dz * inv * gamma[c + 2] + beta[c + 2]);
  o.w = f2bf(dw * inv * gamma[c + 3] + beta[c + 3]);
  ((ushort4*)(y + (size_t)row * 1024))[tid] = o;
}

// ---------------- GEMM 256x256: deep-tile phased, double-buffered ----------------
// C = A[M][K](bf16) * BT[N][K](bf16) + bias. BK=64, 8 waves (2Mx4N), wave out 128x64.
// All staging for tile j+1 issued in PHASE 1 of tile j (~3.5 phases of cover before
// the boundary vmcnt(0) drain). XOR swizzle chunk ^= (row&7): pre-swizzled global
// source + swizzled ds_read, linear global_load_lds dest (rule #21).
// Grid MUST be (M/256)*(N/256), a multiple of 8 (XCD swizzle), and >= 192 blocks
// (R4 lesson: 64-block launches strand 3/4 of the CUs -> 3x slower than 128-tile).
template <bool GELU, bool RES, bool OUTBF, bool SCALEQ>
__global__ __launch_bounds__(512, 2) void gemm8(
    const unsigned short* __restrict__ A,
    const unsigned short* __restrict__ BT,
    const float* __restrict__ bias,
    const float* __restrict__ res,
    void* __restrict__ out,
    int M, int N, int K) {
  constexpr int SLOT = 512 * 64;         // shorts per LDS slot (A 32KB + B 32KB)
  __shared__ unsigned short lds[2 * SLOT];
  (void)M;

  const int nbn = N / 256;
  const int bid = blockIdx.x;
  const int cpx = (int)gridDim.x >> 3;            // grid % 8 == 0
  const int swzb = (bid & 7) * cpx + (bid >> 3);  // XCD-contiguous chunks
  const int bm = swzb / nbn, bn = swzb % nbn;
  const int tid = threadIdx.x;
  const int lane = tid & 63, quad = lane >> 4, l16 = lane & 15;
  const int wm = tid >> 8, wn = (tid >> 6) & 3;

  const int rs = tid >> 3;
  const int xo = ((tid & 7) ^ (rs & 7)) * 8;
  const unsigned short* aSrc = A + (size_t)(bm * 256 + rs) * K + xo;
  const unsigned short* bSrc = BT + (size_t)(bn * 256 + rs) * K + xo;

  const int sw0 = (quad ^ (l16 & 7)) * 8;
  const int sw1 = ((quad ^ 4) ^ (l16 & 7)) * 8;
  const int aBase = (wm * 128 + l16) * 64;
  const int bBase = 16384 + (wn * 64 + l16) * 64;

  f32x4 acc[8][4];
  const f32x4 z4 = {0.f, 0.f, 0.f, 0.f};
#pragma unroll
  for (int i = 0; i < 8; ++i)
#pragma unroll
    for (int n = 0; n < 4; ++n) acc[i][n] = z4;

  const int NT = K >> 6;
  {  // prologue: stage tile 0 -> slot 0
    unsigned short* dA = lds + (size_t)tid * 8;
    unsigned short* dB = lds + 16384 + (size_t)tid * 8;
#pragma unroll
    for (int u = 0; u < 4; ++u) gload_lds16(aSrc + (size_t)u * 64 * K, dA + u * 4096);
#pragma unroll
    for (int u = 0; u < 4; ++u) gload_lds16(bSrc + (size_t)u * 64 * K, dB + u * 4096);
  }

  for (int j = 0; j < NT; ++j) {
    const int s = j & 1;
    asm volatile("s_waitcnt vmcnt(0) lgkmcnt(0)" ::: "memory");
    __builtin_amdgcn_s_barrier();
    __builtin_amdgcn_sched_barrier(0);
    const unsigned short* Ts = lds + s * SLOT;
    unsigned short* stA = lds + (s ^ 1) * SLOT + (size_t)tid * 8;
    unsigned short* stB = stA + 16384;
    const bool pre = (j + 1 < NT);
    const int kN = (j + 1) << 6;

    bf16x8 af[4][2], bfr[4][2];
    // ---------- phase 1: m-half 0, B n-frags 0..1; issue ALL stage(j+1) ----------
#pragma unroll
    for (int mm = 0; mm < 4; ++mm) {
      af[mm][0] = *(const bf16x8*)(Ts + aBase + mm * 1024 + sw0);
      af[mm][1] = *(const bf16x8*)(Ts + aBase + mm * 1024 + sw1);
    }
#pragma unroll
    for (int nn = 0; nn < 2; ++nn) {
      bfr[nn][0] = *(const bf16x8*)(Ts + bBase + nn * 1024 + sw0);
      bfr[nn][1] = *(const bf16x8*)(Ts + bBase + nn * 1024 + sw1);
    }
    if (pre) {
#pragma unroll
      for (int u = 0; u < 4; ++u)
        gload_lds16(aSrc + (size_t)u * 64 * K + kN, stA + u * 4096);
#pragma unroll
      for (int u = 0; u < 4; ++u)
        gload_lds16(bSrc + (size_t)u * 64 * K + kN, stB + u * 4096);
    }
    __builtin_amdgcn_s_barrier();
    __builtin_amdgcn_s_setprio(1);
#pragma unroll
    for (int mm = 0; mm < 4; ++mm)
#pragma unroll
      for (int nn = 0; nn < 2; ++nn) {
        acc[mm][nn] = __builtin_amdgcn_mfma_f32_16x16x32_bf16(af[mm][0], bfr[nn][0], acc[mm][nn], 0, 0, 0);
        acc[mm][nn] = __builtin_amdgcn_mfma_f32_16x16x32_bf16(af[mm][1], bfr[nn][1], acc[mm][nn], 0, 0, 0);
      }
    __builtin_amdgcn_s_setprio(0);
    // ---------- phase 2: m-half 0, B n-frags 2..3 ----------
#pragma unroll
    for (int nn = 2; nn < 4; ++nn) {
      bfr[nn][0] = *(const bf16x8*)(Ts + bBase + nn * 1024 + sw0);
      bfr[nn][1] = *(const bf16x8*)(Ts + bBase + nn * 1024 + sw1);
    }
    __builtin_amdgcn_s_barrier();
    __builtin_amdgcn_s_setprio(1);
#pragma unroll
    for (int mm = 0; mm < 4; ++mm)
#pragma unroll
      for (int nn = 2; nn < 4; ++nn) {
        acc[mm][nn] = __builtin_amdgcn_mfma_f32_16x16x32_bf16(af[mm][0], bfr[nn][0], acc[mm][nn], 0, 0, 0);
        acc[mm][nn] = __builtin_amdgcn_mfma_f32_16x16x32_bf16(af[mm][1], bfr[nn][1], acc[mm][nn], 0, 0, 0);
      }
    __builtin_amdgcn_s_setprio(0);
    // ---------- phase 3: m-half 1, B n-frags 0..1 ----------
#pragma unroll
    for (int mm = 0; mm < 4; ++mm) {
      af[mm][0] = *(const bf16x8*)(Ts + aBase + 4096 + mm * 1024 + sw0);
      af[mm][1] = *(const bf16x8*)(Ts + aBase + 4096 + mm * 1024 + sw1);
    }
    __builtin_amdgcn_s_barrier();
    __builtin_amdgcn_s_setprio(1);
#pragma unroll
    for (int mm = 0; mm < 4; ++mm)
#pragma unroll
      for (int nn = 0; nn < 2; ++nn) {
        acc[4 + mm][nn] = __builtin_amdgcn_mfma_f32_16x16x32_bf16(af[mm][0], bfr[nn][0], acc[4 + mm][nn], 0, 0, 0);
        acc[4 + mm][nn] = __builtin_amdgcn_mfma_f32_16x16x32_bf16(af[mm][1], bfr[nn][1], acc[4 + mm][nn], 0, 0, 0);
      }
    __builtin_amdgcn_s_setprio(0);
    // ---------- phase 4: m-half 1, B n-frags 2..3 ----------
    __builtin_amdgcn_s_barrier();
    __builtin_amdgcn_s_setprio(1);
#pragma unroll
    for (int mm = 0; mm < 4; ++mm)
#pragma unroll
      for (int nn = 2; nn < 4; ++nn) {
        acc[4 + mm][nn] = __builtin_amdgcn_mfma_f32_16x16x32_bf16(af[mm][0], bfr[nn][0], acc[4 + mm][nn], 0, 0, 0);
        acc[4 + mm][nn] = __builtin_amdgcn_mfma_f32_16x16x32_bf16(af[mm][1], bfr[nn][1], acc[4 + mm][nn], 0, 0, 0);
      }
    __builtin_amdgcn_s_setprio(0);
  }

  // ---------------- epilogue ----------------
#pragma unroll
  for (int mi = 0; mi < 8; ++mi) {
    const int row0 = bm * 256 + wm * 128 + mi * 16 + quad * 4;
#pragma unroll
    for (int ni = 0; ni < 4; ++ni) {
      const int col = bn * 256 + wn * 64 + ni * 16 + l16;
      const float bv = bias[col];
      // 0.125/sqrt(DH) * log2(e): softmax uses exp2
      const float qs = (SCALEQ && col < 1024) ? 0.18033688f : 1.0f;
#pragma unroll
      for (int r = 0; r < 4; ++r) {
        float v = (acc[mi][ni][r] + bv) * qs;
        if (GELU) v = 0.5f * v * (1.0f + erff(v * 0.70710678118654752440f));
        if (RES) v += res[(size_t)(row0 + r) * N + col];
        if (OUTBF)
          ((unsigned short*)out)[(size_t)(row0 + r) * N + col] = f2bf(v);
        else
          ((float*)out)[(size_t)(row0 + r) * N + col] = v;
      }
    }
  }
}

// ---------------- GEMM 128x128: TRIPLE-buffered, depth-2, counted vmcnt ----------------
// 3 LDS slots (96 KB): prologue stages tiles 0,1; iteration j stages tile j+2 into
// tile j-1's slot; boundary waits vmcnt(4) (drains stage(j), issued a FULL tile ago,
// keeps stage(j+1) in flight -- T4: never drain to 0 in the main loop).
template <bool GELU, bool RES, bool OUTBF>
__global__ __launch_bounds__(512, 2) void gemm3s(
    const unsigned short* __restrict__ A,
    const unsigned short* __restrict__ BT,
    const float* __restrict__ bias,
    const float* __restrict__ res,
    void* __restrict__ out,
    int M, int N, int K) {
  constexpr int SLOT = 256 * 64;         // shorts per slot (A 16KB + B 16KB = 32KB)
  __shared__ unsigned short lds[3 * SLOT];
  (void)M;

  const int nbn = N / 128;
  const int bid = blockIdx.x;
  const int cpx = (int)gridDim.x >> 3;            // grid % 8 == 0
  const int swzb = (bid & 7) * cpx + (bid >> 3);
  const int bm = swzb / nbn, bn = swzb % nbn;
  const int tid = threadIdx.x;
  const int lane = tid & 63, quad = lane >> 4, l16 = lane & 15;
  const int wm = tid >> 8, wn = (tid >> 6) & 3;

  const int rs = tid >> 3;
  const int xo = ((tid & 7) ^ (rs & 7)) * 8;
  const unsigned short* aSrc = A + (size_t)(bm * 128 + rs) * K + xo;
  const unsigned short* bSrc = BT + (size_t)(bn * 128 + rs) * K + xo;

  const int sw0 = (quad ^ (l16 & 7)) * 8;
  const int sw1 = ((quad ^ 4) ^ (l16 & 7)) * 8;
  const int aBase = (wm * 64 + l16) * 64;
  const int bBase = 8192 + (wn * 32 + l16) * 64;

  f32x4 acc[4][2];
  const f32x4 z4 = {0.f, 0.f, 0.f, 0.f};
#pragma unroll
  for (int i = 0; i < 4; ++i)
#pragma unroll
    for (int n = 0; n < 2; ++n) acc[i][n] = z4;

  const int NT = K >> 6;
  {  // prologue: tile 0 -> slot 0, tile 1 -> slot 1 (program order: tile 0 first!)
    unsigned short* d0 = lds + (size_t)tid * 8;
    gload_lds16(aSrc, d0);
    gload_lds16(aSrc + (size_t)64 * K, d0 + 4096);
    gload_lds16(bSrc, d0 + 8192);
    gload_lds16(bSrc + (size_t)64 * K, d0 + 8192 + 4096);
    if (NT > 1) {
      unsigned short* d1 = lds + SLOT + (size_t)tid * 8;
      gload_lds16(aSrc + 64, d1);
      gload_lds16(aSrc + (size_t)64 * K + 64, d1 + 4096);
      gload_lds16(bSrc + 64, d1 + 8192);
      gload_lds16(bSrc + (size_t)64 * K + 64, d1 + 8192 + 4096);
    }
  }

  int sl = 0;  // slot of tile j
  for (int j = 0; j < NT; ++j) {
    if (j + 1 < NT)
      asm volatile("s_waitcnt vmcnt(4) lgkmcnt(0)" ::: "memory");
    else
      asm volatile("s_waitcnt vmcnt(0) lgkmcnt(0)" ::: "memory");
    __builtin_amdgcn_s_barrier();
    __builtin_amdgcn_sched_barrier(0);
    const unsigned short* Ts = lds + sl * SLOT;
    const int sl2 = (sl >= 1) ? sl - 1 : 2;  // slot of tile j+2 == slot of tile j-1
    unsigned short* st = lds + sl2 * SLOT + (size_t)tid * 8;

    bf16x8 af[2][2], bfr[2][2];
    // ---------- phase 1: m-half 0 + all B; issue stage(j+2) ----------
#pragma unroll
    for (int mm = 0; mm < 2; ++mm) {
      af[mm][0] = *(const bf16x8*)(Ts + aBase + mm * 1024 + sw0);
      af[mm][1] = *(const bf16x8*)(Ts + aBase + mm * 1024 + sw1);
    }
#pragma unroll
    for (int nn = 0; nn < 2; ++nn) {
      bfr[nn][0] = *(const bf16x8*)(Ts + bBase + nn * 1024 + sw0);
      bfr[nn][1] = *(const bf16x8*)(Ts + bBase + nn * 1024 + sw1);
    }
    if (j + 2 < NT) {
      const int kN = (j + 2) << 6;
      gload_lds16(aSrc + kN, st);
      gload_lds16(aSrc + (size_t)64 * K + kN, st + 4096);
      gload_lds16(bSrc + kN, st + 8192);
      gload_lds16(bSrc + (size_t)64 * K + kN, st + 8192 + 4096);
    }
    __builtin_amdgcn_s_barrier();
    __builtin_amdgcn_s_setprio(1);
#pragma unroll
    for (int mm = 0; mm < 2; ++mm)
#pragma unroll
      for (int nn = 0; nn < 2; ++nn) {
        acc[mm][nn] = __builtin_amdgcn_mfma_f32_16x16x32_bf16(af[mm][0], bfr[nn][0], acc[mm][nn], 0, 0, 0);
        acc[mm][nn] = __builtin_amdgcn_mfma_f32_16x16x32_bf16(af[mm][1], bfr[nn][1], acc[mm][nn], 0, 0, 0);
      }
    __builtin_amdgcn_s_setprio(0);
    // ---------- phase 2: m-half 1 (B regs live) ----------
#pragma unroll
    for (int mm = 0; mm < 2; ++mm) {
      af[mm][0] = *(const bf16x8*)(Ts + aBase + 2048 + mm * 1024 + sw0);
      af[mm][1] = *(const bf16x8*)(Ts + aBase + 2048 + mm * 1024 + sw1);
    }
    __builtin_amdgcn_s_barrier();
    __builtin_amdgcn_s_setprio(1);
#pragma unroll
    for (int mm = 0; mm < 2; ++mm)
#pragma unroll
      for (int nn = 0; nn < 2; ++nn) {
        acc[2 + mm][nn] = __builtin_amdgcn_mfma_f32_16x16x32_bf16(af[mm][0], bfr[nn][0], acc[2 + mm][nn], 0, 0, 0);
        acc[2 + mm][nn] = __builtin_amdgcn_mfma_f32_16x16x32_bf16(af[mm][1], bfr[nn][1], acc[2 + mm][nn], 0, 0, 0);
      }
    __builtin_amdgcn_s_setprio(0);
    sl = (sl == 2) ? 0 : sl + 1;
  }

  // ---------------- epilogue ----------------
#pragma unroll
  for (int mi = 0; mi < 4; ++mi) {
    const int row0 = bm * 128 + wm * 64 + mi * 16 + quad * 4;
#pragma unroll
    for (int ni = 0; ni < 2; ++ni) {
      const int col = bn * 128 + wn * 32 + ni * 16 + l16;
      const float bv = bias[col];
#pragma unroll
      for (int r = 0; r < 4; ++r) {
        float v = acc[mi][ni][r] + bv;
        if (GELU) v = 0.5f * v * (1.0f + erff(v * 0.70710678118654752440f));
        if (RES) v += res[(size_t)(row0 + r) * N + col];
        if (OUTBF)
          ((unsigned short*)out)[(size_t)(row0 + r) * N + col] = f2bf(v);
        else
          ((float*)out)[(size_t)(row0 + r) * N + col] = v;
      }
    }
  }
}

// ---------------- prep K/V tiles for attention (fragment-major) ----------------
// K: Kp[h][t][c][kv 64][8]  (c = d-chunk 0..7)  -> wave frag load = 2x512B contiguous
// V: Vp[h][t][c][d 64][8]   (c = kv-chunk 0..7) -> wave frag load = 2x512B contiguous
__global__ __launch_bounds__(256) void prep_kv(const unsigned short* __restrict__ qkv,
                                               unsigned short* __restrict__ Kp,
                                               unsigned short* __restrict__ Vp) {
  __shared__ unsigned short Vt[64 * 64];   // [d][kv]
  int t = blockIdx.x, h = blockIdx.y;
  int tid = threadIdx.x;
  const int r2 = tid >> 3, c0 = (tid & 7) * 8;
  size_t tb = ((size_t)h * 64 + t) * 4096;
  {
    const unsigned short* kp = qkv + (size_t)(t * 64 + r2) * 3072 + 1024 + h * 64 + c0;
    uint4 k0 = *(const uint4*)kp;
    uint4 k1 = *(const uint4*)(kp + (size_t)32 * 3072);
    int c = c0 >> 3;
    *(uint4*)(Kp + tb + c * 512 + r2 * 8) = k0;
    *(uint4*)(Kp + tb + c * 512 + (r2 + 32) * 8) = k1;
  }
  {
    const unsigned short* vp = qkv + (size_t)(t * 64 + 2 * r2) * 3072 + 2048 + h * 64 + c0;
    uint4 v0 = *(const uint4*)vp;          // kv=2*r2,   d=c0..c0+7
    uint4 v1 = *(const uint4*)(vp + 3072); // kv=2*r2+1
    const unsigned short* p0 = (const unsigned short*)&v0;
    const unsigned short* p1 = (const unsigned short*)&v1;
#pragma unroll
    for (int dd = 0; dd < 8; dd++) {
      unsigned int pk = (unsigned int)p0[dd] | ((unsigned int)p1[dd] << 16);
      *(unsigned int*)&Vt[(c0 + dd) * 64 + 2 * r2] = pk;
    }
  }
  __syncthreads();
#pragma unroll
  for (int u0 = 0; u0 < 2; u0++) {
    int u = tid + u0 * 256;           // 0..511 ; c = u>>6, d = u&63
    *(uint4*)(Vp + tb + u * 8) = *(const uint4*)&Vt[(u & 63) * 64 + (u >> 6) * 8];
  }
}

// ---------------- Flash attention: fragment-major K/V -> ctx[S][1024] bf16 ----------------
// R6 restructure: grid (S/128, H) = 512 blocks (= exactly 2/CU, no packing tail).
// Block = 4 INDEPENDENT waves, each owning a 32-q row band over the FULL kv range
// (128 half-tile iterations). No cross-wave combine, no comb LDS (16.9KB -> 512B),
// single __syncthreads at the epilogue for the per-wave row-sum table.
// Q + P in registers; every MFMA fragment is a coalesced global load from the
// prepped layouts (L2/L3-resident). No-max base-2 softmax (0.125*log2e folded
// into Q by the QKV epilogue). R3 lesson: keep VGPR tight (no K/V reg dbuf).
__global__ __launch_bounds__(256, 3) void attn_kernel(const unsigned short* __restrict__ qkv,
                                                      const unsigned short* __restrict__ Kp,
                                                      const unsigned short* __restrict__ Vp,
                                                      unsigned short* __restrict__ ctx) {
  __shared__ float lpw[4 * 32];         // [wave][q] row sums
  int qt = blockIdx.x, h = blockIdx.y;
  int tid = threadIdx.x;
  int w = tid >> 6, lane = tid & 63;
  int l31 = lane & 31, hi = lane >> 5;

  // Q fragments (B-operand: n=q=l31, k=d). Pre-scaled by 0.125*log2e in QKV epilogue.
  bf16x8 qf[4];
  {
    const unsigned short* qp = qkv + (size_t)(qt * 128 + w * 32 + l31) * 3072 + h * 64 + hi * 8;
#pragma unroll
    for (int kk = 0; kk < 4; kk++) qf[kk] = *(const bf16x8*)(qp + kk * 16);
  }

  const size_t hb = (size_t)h * 64 * 4096;
  // K frag (u, kk): kB + (u>>1)*4096 + (u&1)*256 + kk*1024   (u&1 = kv half of tile)
  const unsigned short* kB = Kp + hb + hi * 512 + l31 * 8;
  // V frag (u, kk): vB + (u>>1)*4096 + (u&1)*2048 + kk*1024 (+256 for d-high half)
  const unsigned short* vB = Vp + hb + hi * 512 + l31 * 8;

  f32x16 accO0, accO1;
  f32x2 lp2 = {0.f, 0.f};
#pragma unroll
  for (int r = 0; r < 16; r++) { accO0[r] = 0.f; accO1[r] = 0.f; }

  bf16x8 kf[4];
#pragma unroll
  for (int kk = 0; kk < 4; kk++) kf[kk] = *(const bf16x8*)(kB + kk * 1024);

  for (int u = 0; u < 128; u++) {
    // issue V(u) early: consumed after QK + softmax (~200 cyc later)
    const unsigned short* vt = vB + (size_t)(u >> 1) * 4096 + (u & 1) * 2048;
    bf16x8 vA0 = *(const bf16x8*)(vt);
    bf16x8 vA1 = *(const bf16x8*)(vt + 1024);
    bf16x8 vB0 = *(const bf16x8*)(vt + 256);
    bf16x8 vB1 = *(const bf16x8*)(vt + 1024 + 256);

    // S^T tile [32 kv][32 q]: A = K (m=kv), B = Q^T (n=q)
    f32x16 accS;
#pragma unroll
    for (int r = 0; r < 16; r++) accS[r] = 0.f;
#pragma unroll
    for (int kk = 0; kk < 4; kk++)
      accS = __builtin_amdgcn_mfma_f32_32x32x16_bf16(kf[kk], qf[kk], accS, 0, 0, 0);

    // issue K(u+1): consumed after softmax + PV (~200 cyc later)
    if (u < 127) {
      const int un = u + 1;
      const unsigned short* kt = kB + (size_t)(un >> 1) * 4096 + (un & 1) * 256;
#pragma unroll
      for (int kk = 0; kk < 4; kk++) kf[kk] = *(const bf16x8*)(kt + kk * 1024);
    }

    // P = 2^S; packed row-sum; truncation-pack pairs to bf16
    unsigned int pd[8];
#pragma unroll
    for (int i = 0; i < 8; i++) {
      float a = __builtin_amdgcn_exp2f(accS[2 * i]);
      float b = __builtin_amdgcn_exp2f(accS[2 * i + 1]);
      f32x2 ab = {a, b};
      lp2 += ab;
      pd[i] = __builtin_amdgcn_perm(__float_as_uint(b), __float_as_uint(a), 0x07060302);
    }
    // assemble P A-fragments: one v_permlane32_swap per dword pair
    asm("v_permlane32_swap_b32 %0, %1" : "+v"(pd[0]), "+v"(pd[2]));
    asm("v_permlane32_swap_b32 %0, %1" : "+v"(pd[1]), "+v"(pd[3]));
    asm("v_permlane32_swap_b32 %0, %1" : "+v"(pd[4]), "+v"(pd[6]));
    asm("v_permlane32_swap_b32 %0, %1" : "+v"(pd[5]), "+v"(pd[7]));
    u32x4 f0 = {pd[0], pd[1], pd[2], pd[3]};
    u32x4 f1 = {pd[4], pd[5], pd[6], pd[7]};
    bf16x8 pa0 = __builtin_bit_cast(bf16x8, f0);
    bf16x8 pa1 = __builtin_bit_cast(bf16x8, f1);

    // O += P V
    accO0 = __builtin_amdgcn_mfma_f32_32x32x16_bf16(pa0, vA0, accO0, 0, 0, 0);
    accO1 = __builtin_amdgcn_mfma_f32_32x32x16_bf16(pa0, vB0, accO1, 0, 0, 0);
    accO0 = __builtin_amdgcn_mfma_f32_32x32x16_bf16(pa1, vA1, accO0, 0, 0, 0);
    accO1 = __builtin_amdgcn_mfma_f32_32x32x16_bf16(pa1, vB1, accO1, 0, 0, 0);
  }

  // ---- epilogue: wave-local row-sum redistribute + scaled store ----
  float lp = lp2.x + lp2.y;
  lp += __shfl_xor(lp, 32);             // both hi halves now hold the full sum
  if (hi == 0) lpw[w * 32 + l31] = lp;  // q = l31
  __syncthreads();
#pragma unroll
  for (int r = 0; r < 16; r++) {
    int q = (r & 3) + 8 * (r >> 2) + 4 * hi;
    float inv = 1.0f / lpw[w * 32 + q];
    int row = qt * 128 + w * 32 + q;
    size_t o = (size_t)row * 1024 + h * 64;
    ctx[o + l31] = f2bf(accO0[r] * inv);
    ctx[o + 32 + l31] = f2bf(accO1[r] * inv);
  }
}

// ---------------- launcher ----------------
extern "C" void kernel_launch(void* const* d_in, const int* in_sizes, int n_in,
                              void* d_out, int out_size, void* d_ws, size_t ws_size,
                              hipStream_t stream) {
  const float* x   = (const float*)d_in[0];
  const float* Wq  = (const float*)d_in[1];
  const float* bq  = (const float*)d_in[2];
  const float* Wk  = (const float*)d_in[3];
  const float* bk  = (const float*)d_in[4];
  const float* Wv  = (const float*)d_in[5];
  const float* bv  = (const float*)d_in[6];
  const float* Wo  = (const float*)d_in[7];
  const float* bo  = (const float*)d_in[8];
  const float* g1  = (const float*)d_in[9];
  const float* be1 = (const float*)d_in[10];
  const float* g2  = (const float*)d_in[11];
  const float* be2 = (const float*)d_in[12];
  const float* W1  = (const float*)d_in[13];
  const float* b1  = (const float*)d_in[14];
  const float* W2  = (const float*)d_in[15];
  const float* b2  = (const float*)d_in[16];
  float* out = (float*)d_out;

  char* p = (char*)d_ws;
  unsigned short* WqkvT = (unsigned short*)p; p += (size_t)3072 * 1024 * 2;  // [3072][1024]
  unsigned short* WoT   = (unsigned short*)p; p += (size_t)1024 * 1024 * 2;  // [1024][1024]
  unsigned short* W1T   = (unsigned short*)p; p += (size_t)4096 * 1024 * 2;  // [4096][1024]
  unsigned short* W2T   = (unsigned short*)p; p += (size_t)1024 * 4096 * 2;  // [1024][4096]
  float*          bqkv  = (float*)p;          p += 16384;                    // [3072]
  unsigned short* y1    = (unsigned short*)p; p += (size_t)4096 * 1024 * 2;  // LN out
  unsigned short* qkvb  = (unsigned short*)p; p += (size_t)4096 * 3072 * 2;  // [S][3072]
  unsigned short* ctxb  = (unsigned short*)p; p += (size_t)4096 * 1024 * 2;  // [S][1024]
  float*          x1    = (float*)p;          p += (size_t)4096 * 1024 * 4;  // residual fp32
  unsigned short* Kp    = (unsigned short*)p; p += (size_t)16 * 64 * 4096 * 2;  // prepped K tiles
  unsigned short* Vp    = (unsigned short*)p; p += (size_t)16 * 64 * 4096 * 2;  // prepped V tiles
  unsigned short* hbuf  = qkvb;  // [S][4096] bf16 aliases qkvb (dead by then)

  dim3 b256(256);
  dim3 b512(512);
  // fused preprocessing: 12 concat + 4096 LN1 rows + 12288 transpose tiles
  prep_all<<<dim3(16396), b256, 0, stream>>>(Wq, Wk, Wv, Wo, W1, W2, bq, bk, bv,
                                             x, g1, be1, y1,
                                             WqkvT, WoT, W1T, W2T, bqkv);

  // QKV: M=4096 N=3072 K=1024; 16*12 = 192 blocks
  gemm8<false, false, true, true><<<dim3(192), b512, 0, stream>>>(y1, WqkvT, bqkv, nullptr, qkvb, 4096, 3072, 1024);
  prep_kv<<<dim3(64, 16), b256, 0, stream>>>(qkvb, Kp, Vp);
  attn_kernel<<<dim3(32, 16), b256, 0, stream>>>(qkvb, Kp, Vp, ctxb);
  // Wo: M=4096 N=1024 K=1024; 32*8 = 256 blocks
  gemm3s<false, true, false><<<dim3(256), b512, 0, stream>>>(ctxb, WoT, bo, x, x1, 4096, 1024, 1024);
  ln_kernel<<<4096, b256, 0, stream>>>(x1, g2, be2, y1);
  // W1: M=4096 N=4096 K=1024; 16*16 = 256 blocks
  gemm8<true, false, true, false><<<dim3(256), b512, 0, stream>>>(y1, W1T, b1, nullptr, hbuf, 4096, 4096, 1024);
  // W2: M=4096 N=1024 K=4096; 32*8 = 256 blocks
  gemm3s<false, true, false><<<dim3(256), b512, 0, stream>>>(hbuf, W2T, b2, x1, out, 4096, 1024, 4096);
}

// Round 8
// 361.151 us; speedup vs baseline: 1.0830x; 1.0830x over previous
//
#include <hip/hip_runtime.h>
#include <cstdint>
#include <cstddef>

// S=4096, D=1024, H=16, DH=64, F=4096. fp32 in/out, bf16 MFMA compute.

typedef __attribute__((ext_vector_type(8))) __bf16 bf16x8;
typedef __attribute__((ext_vector_type(4))) float f32x4;
typedef __attribute__((ext_vector_type(2))) float f32x2;
typedef __attribute__((ext_vector_type(16))) float f32x16;
typedef __attribute__((ext_vector_type(4))) unsigned int u32x4;

__device__ inline unsigned short f2bf(float f) {
  unsigned int u = __float_as_uint(f);
  u += 0x7fffu + ((u >> 16) & 1u);   // round-to-nearest-even
  return (unsigned short)(u >> 16);
}

// Branch-free GELU: Abramowitz-Stegun 7.1.26 erf (|eps|<=1.5e-7), ~12 fma + v_exp.
// R7 post-mortem: libm erff in the W1 epilogue drove VALUBusy to 18.8% (vs 5.3%
// for the GELU-free instantiation) and is codegen-fragile across builds.
__device__ inline float gelu_f(float v) {
  float z = v * 0.70710678118654752440f;
  float az = fabsf(z);
  float t = 1.0f / fmaf(0.3275911f, az, 1.0f);
  float p = t * fmaf(t, fmaf(t, fmaf(t, fmaf(t, 1.061405429f, -1.453152027f),
                                     1.421413741f), -0.284496736f), 0.254829592f);
  float e = p * __expf(-az * az);          // = 1 - erf(|z|)
  float erfz = copysignf(1.0f - e, z);
  return 0.5f * v * (1.0f + erfz);
}

__device__ inline void gload_lds16(const unsigned short* g, unsigned short* l) {
  __builtin_amdgcn_global_load_lds(
      (const __attribute__((address_space(1))) void*)g,
      (__attribute__((address_space(3))) void*)l, 16, 0, 0);
}

// ---------------- fused preprocessing: 6 transposes + bias concat + LN1, ONE launch ----------------
// Blocks 0..11: concat bqkv. Blocks 12..4107: LN1 rows (independent of weights).
// Blocks 4108..: 32x32 transpose tiles for Wq,Wk,Wv,Wo (1024 each), W1 (4096), W2 (4096).
// Grid = 12 + 4096 + 12288 = 16396.
__global__ __launch_bounds__(256) void prep_all(
    const float* __restrict__ Wq, const float* __restrict__ Wk,
    const float* __restrict__ Wv, const float* __restrict__ Wo,
    const float* __restrict__ W1, const float* __restrict__ W2,
    const float* __restrict__ bq, const float* __restrict__ bk,
    const float* __restrict__ bv,
    const float* __restrict__ x, const float* __restrict__ g1,
    const float* __restrict__ be1, unsigned short* __restrict__ y1,
    unsigned short* __restrict__ WqkvT, unsigned short* __restrict__ WoT,
    unsigned short* __restrict__ W1T, unsigned short* __restrict__ W2T,
    float* __restrict__ bqkv) {
  int b = blockIdx.x;
  const int tid = threadIdx.x;
  if (b < 12) {  // bias concat: 3072 floats
    int i = b * 256 + tid;
    bqkv[i] = (i < 1024) ? bq[i] : (i < 2048 ? bk[i - 1024] : bv[i - 2048]);
    return;
  }
  b -= 12;
  if (b < 4096) {  // ---- LayerNorm row b -> y1 (bf16) ----
    const int row = b;
    const float4 v = ((const float4*)(x + (size_t)row * 1024))[tid];
    float s = v.x + v.y + v.z + v.w;
#pragma unroll
    for (int off = 1; off < 64; off <<= 1) s += __shfl_xor(s, off);
    __shared__ float red1[4], red2[4];
    int wave = tid >> 6;
    if ((tid & 63) == 0) red1[wave] = s;
    __syncthreads();
    float mu = (red1[0] + red1[1] + red1[2] + red1[3]) * (1.0f / 1024.0f);
    float dx = v.x - mu, dy = v.y - mu, dz = v.z - mu, dw = v.w - mu;
    float s2 = dx * dx + dy * dy + dz * dz + dw * dw;
#pragma unroll
    for (int off = 1; off < 64; off <<= 1) s2 += __shfl_xor(s2, off);
    if ((tid & 63) == 0) red2[wave] = s2;
    __syncthreads();
    float var = (red2[0] + red2[1] + red2[2] + red2[3]) * (1.0f / 1024.0f);
    float inv = rsqrtf(var + 1e-6f);
    int c = tid * 4;
    ushort4 o;
    o.x = f2bf(dx * inv * g1[c + 0] + be1[c + 0]);
    o.y = f2bf(dy * inv * g1[c + 1] + be1[c + 1]);
    o.z = f2bf(dz * inv * g1[c + 2] + be1[c + 2]);
    o.w = f2bf(dw * inv * g1[c + 3] + be1[c + 3]);
    ((ushort4*)(y1 + (size_t)row * 1024))[tid] = o;
    return;
  }
  b -= 4096;
  const float* in;
  unsigned short* out;
  int K, N, nbx;
  if (b < 4096) {               // Wq/Wk/Wv/Wo: 1024x1024 each, 1024 tiles each
    const int sel = b >> 10;
    in = (sel == 0) ? Wq : (sel == 1) ? Wk : (sel == 2) ? Wv : Wo;
    out = (sel == 3) ? WoT : WqkvT + (size_t)sel * 1024 * 1024;
    K = 1024; N = 1024; nbx = 32; b &= 1023;
  } else if (b < 8192) {        // W1: [1024][4096] -> W1T [4096][1024]
    b -= 4096; in = W1; out = W1T; K = 1024; N = 4096; nbx = 128;
  } else {                      // W2: [4096][1024] -> W2T [1024][4096]
    b -= 8192; in = W2; out = W2T; K = 4096; N = 1024; nbx = 32;
  }
  const int nb = (b % nbx) * 32, kb = (b / nbx) * 32;
  __shared__ float t[32][33];
  const int tx = tid & 31, ty = tid >> 5;  // 32 x 8
#pragma unroll
  for (int i = 0; i < 32; i += 8)
    t[ty + i][tx] = in[(size_t)(kb + ty + i) * N + nb + tx];
  __syncthreads();
#pragma unroll
  for (int i = 0; i < 32; i += 8)
    out[(size_t)(nb + ty + i) * K + kb + tx] = f2bf(t[tx][ty + i]);
}

// ---------------- LayerNorm row (D=1024), output bf16 (used for LN2) ----------------
__global__ __launch_bounds__(256) void ln_kernel(const float* __restrict__ x,
                                                 const float* __restrict__ gamma,
                                                 const float* __restrict__ beta,
                                                 unsigned short* __restrict__ y) {
  int row = blockIdx.x, tid = threadIdx.x;
  const float4 v = ((const float4*)(x + (size_t)row * 1024))[tid];
  float s = v.x + v.y + v.z + v.w;
#pragma unroll
  for (int off = 1; off < 64; off <<= 1) s += __shfl_xor(s, off);
  __shared__ float red1[4], red2[4];
  int wave = tid >> 6;
  if ((tid & 63) == 0) red1[wave] = s;
  __syncthreads();
  float mu = (red1[0] + red1[1] + red1[2] + red1[3]) * (1.0f / 1024.0f);
  float dx = v.x - mu, dy = v.y - mu, dz = v.z - mu, dw = v.w - mu;
  float s2 = dx * dx + dy * dy + dz * dz + dw * dw;
#pragma unroll
  for (int off = 1; off < 64; off <<= 1) s2 += __shfl_xor(s2, off);
  if ((tid & 63) == 0) red2[wave] = s2;
  __syncthreads();
  float var = (red2[0] + red2[1] + red2[2] + red2[3]) * (1.0f / 1024.0f);
  float inv = rsqrtf(var + 1e-6f);
  int c = tid * 4;
  ushort4 o;
  o.x = f2bf(dx * inv * gamma[c + 0] + beta[c + 0]);
  o.y = f2bf(dy * inv * gamma[c + 1] + beta[c + 1]);
  o.z = f2bf(dz * inv * gamma[c + 2] + beta[c + 2]);
  o.w = f2bf(dw * inv * gamma[c + 3] + beta[c + 3]);
  ((ushort4*)(y + (size_t)row * 1024))[tid] = o;
}

// ---------------- GEMM 256x256: deep-tile phased, double-buffered (QKV, W1) ----------------
// C = A[M][K](bf16) * BT[N][K](bf16) + bias. BK=64, 8 waves (2Mx4N), wave out 128x64.
// All staging for tile j+1 issued in PHASE 1 of tile j (~3.5 phases of cover before
// the boundary vmcnt(0) drain). XOR swizzle chunk ^= (row&7): pre-swizzled global
// source + swizzled ds_read, linear global_load_lds dest (rule #21).
// Grid MUST be (M/256)*(N/256), a multiple of 8 (XCD swizzle), and >= 192 blocks.
template <bool GELU, bool RES, bool OUTBF, bool SCALEQ>
__global__ __launch_bounds__(512, 2) void gemm8(
    const unsigned short* __restrict__ A,
    const unsigned short* __restrict__ BT,
    const float* __restrict__ bias,
    const float* __restrict__ res,
    void* __restrict__ out,
    int M, int N, int K) {
  constexpr int SLOT = 512 * 64;         // shorts per LDS slot (A 32KB + B 32KB)
  __shared__ unsigned short lds[2 * SLOT];
  (void)M;

  const int nbn = N / 256;
  const int bid = blockIdx.x;
  const int cpx = (int)gridDim.x >> 3;            // grid % 8 == 0
  const int swzb = (bid & 7) * cpx + (bid >> 3);  // XCD-contiguous chunks
  const int bm = swzb / nbn, bn = swzb % nbn;
  const int tid = threadIdx.x;
  const int lane = tid & 63, quad = lane >> 4, l16 = lane & 15;
  const int wm = tid >> 8, wn = (tid >> 6) & 3;

  const int rs = tid >> 3;
  const int xo = ((tid & 7) ^ (rs & 7)) * 8;
  const unsigned short* aSrc = A + (size_t)(bm * 256 + rs) * K + xo;
  const unsigned short* bSrc = BT + (size_t)(bn * 256 + rs) * K + xo;

  const int sw0 = (quad ^ (l16 & 7)) * 8;
  const int sw1 = ((quad ^ 4) ^ (l16 & 7)) * 8;
  const int aBase = (wm * 128 + l16) * 64;
  const int bBase = 16384 + (wn * 64 + l16) * 64;

  f32x4 acc[8][4];
  const f32x4 z4 = {0.f, 0.f, 0.f, 0.f};
#pragma unroll
  for (int i = 0; i < 8; ++i)
#pragma unroll
    for (int n = 0; n < 4; ++n) acc[i][n] = z4;

  const int NT = K >> 6;
  {  // prologue: stage tile 0 -> slot 0
    unsigned short* dA = lds + (size_t)tid * 8;
    unsigned short* dB = lds + 16384 + (size_t)tid * 8;
#pragma unroll
    for (int u = 0; u < 4; ++u) gload_lds16(aSrc + (size_t)u * 64 * K, dA + u * 4096);
#pragma unroll
    for (int u = 0; u < 4; ++u) gload_lds16(bSrc + (size_t)u * 64 * K, dB + u * 4096);
  }

  for (int j = 0; j < NT; ++j) {
    const int s = j & 1;
    asm volatile("s_waitcnt vmcnt(0) lgkmcnt(0)" ::: "memory");
    __builtin_amdgcn_s_barrier();
    __builtin_amdgcn_sched_barrier(0);
    const unsigned short* Ts = lds + s * SLOT;
    unsigned short* stA = lds + (s ^ 1) * SLOT + (size_t)tid * 8;
    unsigned short* stB = stA + 16384;
    const bool pre = (j + 1 < NT);
    const int kN = (j + 1) << 6;

    bf16x8 af[4][2], bfr[4][2];
    // ---------- phase 1: m-half 0, B n-frags 0..1; issue ALL stage(j+1) ----------
#pragma unroll
    for (int mm = 0; mm < 4; ++mm) {
      af[mm][0] = *(const bf16x8*)(Ts + aBase + mm * 1024 + sw0);
      af[mm][1] = *(const bf16x8*)(Ts + aBase + mm * 1024 + sw1);
    }
#pragma unroll
    for (int nn = 0; nn < 2; ++nn) {
      bfr[nn][0] = *(const bf16x8*)(Ts + bBase + nn * 1024 + sw0);
      bfr[nn][1] = *(const bf16x8*)(Ts + bBase + nn * 1024 + sw1);
    }
    if (pre) {
#pragma unroll
      for (int u = 0; u < 4; ++u)
        gload_lds16(aSrc + (size_t)u * 64 * K + kN, stA + u * 4096);
#pragma unroll
      for (int u = 0; u < 4; ++u)
        gload_lds16(bSrc + (size_t)u * 64 * K + kN, stB + u * 4096);
    }
    __builtin_amdgcn_s_barrier();
    __builtin_amdgcn_s_setprio(1);
#pragma unroll
    for (int mm = 0; mm < 4; ++mm)
#pragma unroll
      for (int nn = 0; nn < 2; ++nn) {
        acc[mm][nn] = __builtin_amdgcn_mfma_f32_16x16x32_bf16(af[mm][0], bfr[nn][0], acc[mm][nn], 0, 0, 0);
        acc[mm][nn] = __builtin_amdgcn_mfma_f32_16x16x32_bf16(af[mm][1], bfr[nn][1], acc[mm][nn], 0, 0, 0);
      }
    __builtin_amdgcn_s_setprio(0);
    // ---------- phase 2: m-half 0, B n-frags 2..3 ----------
#pragma unroll
    for (int nn = 2; nn < 4; ++nn) {
      bfr[nn][0] = *(const bf16x8*)(Ts + bBase + nn * 1024 + sw0);
      bfr[nn][1] = *(const bf16x8*)(Ts + bBase + nn * 1024 + sw1);
    }
    __builtin_amdgcn_s_barrier();
    __builtin_amdgcn_s_setprio(1);
#pragma unroll
    for (int mm = 0; mm < 4; ++mm)
#pragma unroll
      for (int nn = 2; nn < 4; ++nn) {
        acc[mm][nn] = __builtin_amdgcn_mfma_f32_16x16x32_bf16(af[mm][0], bfr[nn][0], acc[mm][nn], 0, 0, 0);
        acc[mm][nn] = __builtin_amdgcn_mfma_f32_16x16x32_bf16(af[mm][1], bfr[nn][1], acc[mm][nn], 0, 0, 0);
      }
    __builtin_amdgcn_s_setprio(0);
    // ---------- phase 3: m-half 1, B n-frags 0..1 ----------
#pragma unroll
    for (int mm = 0; mm < 4; ++mm) {
      af[mm][0] = *(const bf16x8*)(Ts + aBase + 4096 + mm * 1024 + sw0);
      af[mm][1] = *(const bf16x8*)(Ts + aBase + 4096 + mm * 1024 + sw1);
    }
    __builtin_amdgcn_s_barrier();
    __builtin_amdgcn_s_setprio(1);
#pragma unroll
    for (int mm = 0; mm < 4; ++mm)
#pragma unroll
      for (int nn = 0; nn < 2; ++nn) {
        acc[4 + mm][nn] = __builtin_amdgcn_mfma_f32_16x16x32_bf16(af[mm][0], bfr[nn][0], acc[4 + mm][nn], 0, 0, 0);
        acc[4 + mm][nn] = __builtin_amdgcn_mfma_f32_16x16x32_bf16(af[mm][1], bfr[nn][1], acc[4 + mm][nn], 0, 0, 0);
      }
    __builtin_amdgcn_s_setprio(0);
    // ---------- phase 4: m-half 1, B n-frags 2..3 ----------
    __builtin_amdgcn_s_barrier();
    __builtin_amdgcn_s_setprio(1);
#pragma unroll
    for (int mm = 0; mm < 4; ++mm)
#pragma unroll
      for (int nn = 2; nn < 4; ++nn) {
        acc[4 + mm][nn] = __builtin_amdgcn_mfma_f32_16x16x32_bf16(af[mm][0], bfr[nn][0], acc[4 + mm][nn], 0, 0, 0);
        acc[4 + mm][nn] = __builtin_amdgcn_mfma_f32_16x16x32_bf16(af[mm][1], bfr[nn][1], acc[4 + mm][nn], 0, 0, 0);
      }
    __builtin_amdgcn_s_setprio(0);
  }

  // ---------------- epilogue ----------------
#pragma unroll
  for (int mi = 0; mi < 8; ++mi) {
    const int row0 = bm * 256 + wm * 128 + mi * 16 + quad * 4;
#pragma unroll
    for (int ni = 0; ni < 4; ++ni) {
      const int col = bn * 256 + wn * 64 + ni * 16 + l16;
      const float bv = bias[col];
      // 0.125/sqrt(DH) * log2(e): softmax uses exp2
      const float qs = (SCALEQ && col < 1024) ? 0.18033688f : 1.0f;
#pragma unroll
      for (int r = 0; r < 4; ++r) {
        float v = (acc[mi][ni][r] + bv) * qs;
        if (GELU) v = gelu_f(v);
        if (RES) v += res[(size_t)(row0 + r) * N + col];
        if (OUTBF)
          ((unsigned short*)out)[(size_t)(row0 + r) * N + col] = f2bf(v);
        else
          ((float*)out)[(size_t)(row0 + r) * N + col] = v;
      }
    }
  }
}

// ---------------- GEMM 128x64: 4 waves, 48KB LDS -> 2-3 blocks/CU (Wo, W2) ----------------
// R7 post-mortem: 96-131KB-LDS GEMMs are 1 block/CU = one barrier group = every
// vmcnt drain stalls the whole CU. This shape co-schedules 2+ independent blocks
// per CU (m114 cross-block overlap hides the drain). BK=64, waves 2Mx2N, wave out
// 64x32, double-buffered, stage(j+1) issued in the read phase of tile j.
// Grid = (M/128)*(N/64), multiple of 8.
template <bool RES, bool OUTBF>
__global__ __launch_bounds__(256, 3) void gemm4w(
    const unsigned short* __restrict__ A,
    const unsigned short* __restrict__ BT,
    const float* __restrict__ bias,
    const float* __restrict__ res,
    void* __restrict__ out,
    int M, int N, int K) {
  constexpr int SLOT = 192 * 64;          // shorts: A 128x64 (8192) + B 64x64 (4096)
  __shared__ unsigned short lds[2 * SLOT];
  (void)M;

  const int nbn = N / 64;
  const int bid = blockIdx.x;
  const int cpx = (int)gridDim.x >> 3;            // grid % 8 == 0
  const int swzb = (bid & 7) * cpx + (bid >> 3);
  const int bm = swzb / nbn, bn = swzb % nbn;
  const int tid = threadIdx.x;
  const int lane = tid & 63, quad = lane >> 4, l16 = lane & 15;
  const int wm = tid >> 7, wn = (tid >> 6) & 1;

  const int rs = tid >> 3;                        // 0..31
  const int xo = ((tid & 7) ^ (rs & 7)) * 8;      // pre-swizzled source chunk
  const unsigned short* aSrc = A + (size_t)(bm * 128 + rs) * K + xo;
  const unsigned short* bSrc = BT + (size_t)(bn * 64 + rs) * K + xo;

  const int sw0 = (quad ^ (l16 & 7)) * 8;
  const int sw1 = ((quad ^ 4) ^ (l16 & 7)) * 8;
  const int aBase = (wm * 64 + l16) * 64;
  const int bBase = 8192 + (wn * 32 + l16) * 64;

  f32x4 acc[4][2];
  const f32x4 z4 = {0.f, 0.f, 0.f, 0.f};
#pragma unroll
  for (int i = 0; i < 4; ++i)
#pragma unroll
    for (int n = 0; n < 2; ++n) acc[i][n] = z4;

  const int NT = K >> 6;
  {  // prologue: stage tile 0 -> slot 0 (A: 4 rounds of 32 rows, B: 2 rounds)
    unsigned short* d = lds + (size_t)tid * 8;
#pragma unroll
    for (int u = 0; u < 4; ++u) gload_lds16(aSrc + (size_t)u * 32 * K, d + u * 2048);
#pragma unroll
    for (int u = 0; u < 2; ++u) gload_lds16(bSrc + (size_t)u * 32 * K, d + 8192 + u * 2048);
  }

  for (int j = 0; j < NT; ++j) {
    const int s = j & 1;
    asm volatile("s_waitcnt vmcnt(0) lgkmcnt(0)" ::: "memory");
    __builtin_amdgcn_s_barrier();
    __builtin_amdgcn_sched_barrier(0);
    const unsigned short* Ts = lds + s * SLOT;
    unsigned short* st = lds + (s ^ 1) * SLOT + (size_t)tid * 8;

    bf16x8 af[4][2], bfr[2][2];
#pragma unroll
    for (int mm = 0; mm < 4; ++mm) {
      af[mm][0] = *(const bf16x8*)(Ts + aBase + mm * 1024 + sw0);
      af[mm][1] = *(const bf16x8*)(Ts + aBase + mm * 1024 + sw1);
    }
#pragma unroll
    for (int nn = 0; nn < 2; ++nn) {
      bfr[nn][0] = *(const bf16x8*)(Ts + bBase + nn * 1024 + sw0);
      bfr[nn][1] = *(const bf16x8*)(Ts + bBase + nn * 1024 + sw1);
    }
    if (j + 1 < NT) {
      const int kN = (j + 1) << 6;
#pragma unroll
      for (int u = 0; u < 4; ++u) gload_lds16(aSrc + (size_t)u * 32 * K + kN, st + u * 2048);
#pragma unroll
      for (int u = 0; u < 2; ++u) gload_lds16(bSrc + (size_t)u * 32 * K + kN, st + 8192 + u * 2048);
    }
    __builtin_amdgcn_s_barrier();
    __builtin_amdgcn_s_setprio(1);
#pragma unroll
    for (int mm = 0; mm < 4; ++mm)
#pragma unroll
      for (int nn = 0; nn < 2; ++nn) {
        acc[mm][nn] = __builtin_amdgcn_mfma_f32_16x16x32_bf16(af[mm][0], bfr[nn][0], acc[mm][nn], 0, 0, 0);
        acc[mm][nn] = __builtin_amdgcn_mfma_f32_16x16x32_bf16(af[mm][1], bfr[nn][1], acc[mm][nn], 0, 0, 0);
      }
    __builtin_amdgcn_s_setprio(0);
  }

  // ---------------- epilogue ----------------
#pragma unroll
  for (int mi = 0; mi < 4; ++mi) {
    const int row0 = bm * 128 + wm * 64 + mi * 16 + quad * 4;
#pragma unroll
    for (int ni = 0; ni < 2; ++ni) {
      const int col = bn * 64 + wn * 32 + ni * 16 + l16;
      const float bv = bias[col];
#pragma unroll
      for (int r = 0; r < 4; ++r) {
        float v = acc[mi][ni][r] + bv;
        if (RES) v += res[(size_t)(row0 + r) * N + col];
        if (OUTBF)
          ((unsigned short*)out)[(size_t)(row0 + r) * N + col] = f2bf(v);
        else
          ((float*)out)[(size_t)(row0 + r) * N + col] = v;
      }
    }
  }
}

// ---------------- prep K/V tiles for attention (fragment-major) ----------------
// K: Kp[h][t][c][kv 64][8]  (c = d-chunk 0..7)  -> wave frag load = 2x512B contiguous
// V: Vp[h][t][c][d 64][8]   (c = kv-chunk 0..7) -> wave frag load = 2x512B contiguous
__global__ __launch_bounds__(256) void prep_kv(const unsigned short* __restrict__ qkv,
                                               unsigned short* __restrict__ Kp,
                                               unsigned short* __restrict__ Vp) {
  __shared__ unsigned short Vt[64 * 64];   // [d][kv]
  int t = blockIdx.x, h = blockIdx.y;
  int tid = threadIdx.x;
  const int r2 = tid >> 3, c0 = (tid & 7) * 8;
  size_t tb = ((size_t)h * 64 + t) * 4096;
  {
    const unsigned short* kp = qkv + (size_t)(t * 64 + r2) * 3072 + 1024 + h * 64 + c0;
    uint4 k0 = *(const uint4*)kp;
    uint4 k1 = *(const uint4*)(kp + (size_t)32 * 3072);
    int c = c0 >> 3;
    *(uint4*)(Kp + tb + c * 512 + r2 * 8) = k0;
    *(uint4*)(Kp + tb + c * 512 + (r2 + 32) * 8) = k1;
  }
  {
    const unsigned short* vp = qkv + (size_t)(t * 64 + 2 * r2) * 3072 + 2048 + h * 64 + c0;
    uint4 v0 = *(const uint4*)vp;          // kv=2*r2,   d=c0..c0+7
    uint4 v1 = *(const uint4*)(vp + 3072); // kv=2*r2+1
    const unsigned short* p0 = (const unsigned short*)&v0;
    const unsigned short* p1 = (const unsigned short*)&v1;
#pragma unroll
    for (int dd = 0; dd < 8; dd++) {
      unsigned int pk = (unsigned int)p0[dd] | ((unsigned int)p1[dd] << 16);
      *(unsigned int*)&Vt[(c0 + dd) * 64 + 2 * r2] = pk;
    }
  }
  __syncthreads();
#pragma unroll
  for (int u0 = 0; u0 < 2; u0++) {
    int u = tid + u0 * 256;           // 0..511 ; c = u>>6, d = u&63
    *(uint4*)(Vp + tb + u * 8) = *(const uint4*)&Vt[(u & 63) * 64 + (u >> 6) * 8];
  }
}

// ---------------- Flash attention: fragment-major K/V -> ctx[S][1024] bf16 ----------------
// grid (S/128, H) = 512 blocks (2/CU). Block = 4 INDEPENDENT waves, each owning a
// 32-q row band over the FULL kv range (128 half-tile iterations). No cross-wave
// combine; single __syncthreads at the epilogue for the per-wave row-sum table.
// Q + P in registers; every MFMA fragment is a coalesced global load from the
// prepped layouts (L2/L3-resident). No-max base-2 softmax (0.125*log2e folded
// into Q by the QKV epilogue). R3 lesson: keep VGPR tight (no K/V reg dbuf).
__global__ __launch_bounds__(256, 3) void attn_kernel(const unsigned short* __restrict__ qkv,
                                                      const unsigned short* __restrict__ Kp,
                                                      const unsigned short* __restrict__ Vp,
                                                      unsigned short* __restrict__ ctx) {
  __shared__ float lpw[4 * 32];         // [wave][q] row sums
  int qt = blockIdx.x, h = blockIdx.y;
  int tid = threadIdx.x;
  int w = tid >> 6, lane = tid & 63;
  int l31 = lane & 31, hi = lane >> 5;

  // Q fragments (B-operand: n=q=l31, k=d). Pre-scaled by 0.125*log2e in QKV epilogue.
  bf16x8 qf[4];
  {
    const unsigned short* qp = qkv + (size_t)(qt * 128 + w * 32 + l31) * 3072 + h * 64 + hi * 8;
#pragma unroll
    for (int kk = 0; kk < 4; kk++) qf[kk] = *(const bf16x8*)(qp + kk * 16);
  }

  const size_t hb = (size_t)h * 64 * 4096;
  // K frag (u, kk): kB + (u>>1)*4096 + (u&1)*256 + kk*1024   (u&1 = kv half of tile)
  const unsigned short* kB = Kp + hb + hi * 512 + l31 * 8;
  // V frag (u, kk): vB + (u>>1)*4096 + (u&1)*2048 + kk*1024 (+256 for d-high half)
  const unsigned short* vB = Vp + hb + hi * 512 + l31 * 8;

  f32x16 accO0, accO1;
  f32x2 lp2 = {0.f, 0.f};
#pragma unroll
  for (int r = 0; r < 16; r++) { accO0[r] = 0.f; accO1[r] = 0.f; }

  bf16x8 kf[4];
#pragma unroll
  for (int kk = 0; kk < 4; kk++) kf[kk] = *(const bf16x8*)(kB + kk * 1024);

  for (int u = 0; u < 128; u++) {
    // issue V(u) early: consumed after QK + softmax (~200 cyc later)
    const unsigned short* vt = vB + (size_t)(u >> 1) * 4096 + (u & 1) * 2048;
    bf16x8 vA0 = *(const bf16x8*)(vt);
    bf16x8 vA1 = *(const bf16x8*)(vt + 1024);
    bf16x8 vB0 = *(const bf16x8*)(vt + 256);
    bf16x8 vB1 = *(const bf16x8*)(vt + 1024 + 256);

    // S^T tile [32 kv][32 q]: A = K (m=kv), B = Q^T (n=q)
    f32x16 accS;
#pragma unroll
    for (int r = 0; r < 16; r++) accS[r] = 0.f;
#pragma unroll
    for (int kk = 0; kk < 4; kk++)
      accS = __builtin_amdgcn_mfma_f32_32x32x16_bf16(kf[kk], qf[kk], accS, 0, 0, 0);

    // issue K(u+1): consumed after softmax + PV (~200 cyc later)
    if (u < 127) {
      const int un = u + 1;
      const unsigned short* kt = kB + (size_t)(un >> 1) * 4096 + (un & 1) * 256;
#pragma unroll
      for (int kk = 0; kk < 4; kk++) kf[kk] = *(const bf16x8*)(kt + kk * 1024);
    }

    // P = 2^S; packed row-sum; truncation-pack pairs to bf16
    unsigned int pd[8];
#pragma unroll
    for (int i = 0; i < 8; i++) {
      float a = __builtin_amdgcn_exp2f(accS[2 * i]);
      float b = __builtin_amdgcn_exp2f(accS[2 * i + 1]);
      f32x2 ab = {a, b};
      lp2 += ab;
      pd[i] = __builtin_amdgcn_perm(__float_as_uint(b), __float_as_uint(a), 0x07060302);
    }
    // assemble P A-fragments: one v_permlane32_swap per dword pair
    asm("v_permlane32_swap_b32 %0, %1" : "+v"(pd[0]), "+v"(pd[2]));
    asm("v_permlane32_swap_b32 %0, %1" : "+v"(pd[1]), "+v"(pd[3]));
    asm("v_permlane32_swap_b32 %0, %1" : "+v"(pd[4]), "+v"(pd[6]));
    asm("v_permlane32_swap_b32 %0, %1" : "+v"(pd[5]), "+v"(pd[7]));
    u32x4 f0 = {pd[0], pd[1], pd[2], pd[3]};
    u32x4 f1 = {pd[4], pd[5], pd[6], pd[7]};
    bf16x8 pa0 = __builtin_bit_cast(bf16x8, f0);
    bf16x8 pa1 = __builtin_bit_cast(bf16x8, f1);

    // O += P V
    accO0 = __builtin_amdgcn_mfma_f32_32x32x16_bf16(pa0, vA0, accO0, 0, 0, 0);
    accO1 = __builtin_amdgcn_mfma_f32_32x32x16_bf16(pa0, vB0, accO1, 0, 0, 0);
    accO0 = __builtin_amdgcn_mfma_f32_32x32x16_bf16(pa1, vA1, accO0, 0, 0, 0);
    accO1 = __builtin_amdgcn_mfma_f32_32x32x16_bf16(pa1, vB1, accO1, 0, 0, 0);
  }

  // ---- epilogue: wave-local row-sum redistribute + scaled store ----
  float lp = lp2.x + lp2.y;
  lp += __shfl_xor(lp, 32);             // both hi halves now hold the full sum
  if (hi == 0) lpw[w * 32 + l31] = lp;  // q = l31
  __syncthreads();
#pragma unroll
  for (int r = 0; r < 16; r++) {
    int q = (r & 3) + 8 * (r >> 2) + 4 * hi;
    float inv = 1.0f / lpw[w * 32 + q];
    int row = qt * 128 + w * 32 + q;
    size_t o = (size_t)row * 1024 + h * 64;
    ctx[o + l31] = f2bf(accO0[r] * inv);
    ctx[o + 32 + l31] = f2bf(accO1[r] * inv);
  }
}

// ---------------- launcher ----------------
extern "C" void kernel_launch(void* const* d_in, const int* in_sizes, int n_in,
                              void* d_out, int out_size, void* d_ws, size_t ws_size,
                              hipStream_t stream) {
  const float* x   = (const float*)d_in[0];
  const float* Wq  = (const float*)d_in[1];
  const float* bq  = (const float*)d_in[2];
  const float* Wk  = (const float*)d_in[3];
  const float* bk  = (const float*)d_in[4];
  const float* Wv  = (const float*)d_in[5];
  const float* bv  = (const float*)d_in[6];
  const float* Wo  = (const float*)d_in[7];
  const float* bo  = (const float*)d_in[8];
  const float* g1  = (const float*)d_in[9];
  const float* be1 = (const float*)d_in[10];
  const float* g2  = (const float*)d_in[11];
  const float* be2 = (const float*)d_in[12];
  const float* W1  = (const float*)d_in[13];
  const float* b1  = (const float*)d_in[14];
  const float* W2  = (const float*)d_in[15];
  const float* b2  = (const float*)d_in[16];
  float* out = (float*)d_out;

  char* p = (char*)d_ws;
  unsigned short* WqkvT = (unsigned short*)p; p += (size_t)3072 * 1024 * 2;  // [3072][1024]
  unsigned short* WoT   = (unsigned short*)p; p += (size_t)1024 * 1024 * 2;  // [1024][1024]
  unsigned short* W1T   = (unsigned short*)p; p += (size_t)4096 * 1024 * 2;  // [4096][1024]
  unsigned short* W2T   = (unsigned short*)p; p += (size_t)1024 * 4096 * 2;  // [1024][4096]
  float*          bqkv  = (float*)p;          p += 16384;                    // [3072]
  unsigned short* y1    = (unsigned short*)p; p += (size_t)4096 * 1024 * 2;  // LN out
  unsigned short* qkvb  = (unsigned short*)p; p += (size_t)4096 * 3072 * 2;  // [S][3072]
  unsigned short* ctxb  = (unsigned short*)p; p += (size_t)4096 * 1024 * 2;  // [S][1024]
  float*          x1    = (float*)p;          p += (size_t)4096 * 1024 * 4;  // residual fp32
  unsigned short* Kp    = (unsigned short*)p; p += (size_t)16 * 64 * 4096 * 2;  // prepped K tiles
  unsigned short* Vp    = (unsigned short*)p; p += (size_t)16 * 64 * 4096 * 2;  // prepped V tiles
  unsigned short* hbuf  = qkvb;  // [S][4096] bf16 aliases qkvb (dead by then)

  dim3 b256(256);
  dim3 b512(512);
  // fused preprocessing: 12 concat + 4096 LN1 rows + 12288 transpose tiles
  prep_all<<<dim3(16396), b256, 0, stream>>>(Wq, Wk, Wv, Wo, W1, W2, bq, bk, bv,
                                             x, g1, be1, y1,
                                             WqkvT, WoT, W1T, W2T, bqkv);

  // QKV: M=4096 N=3072 K=1024; 16*12 = 192 blocks
  gemm8<false, false, true, true><<<dim3(192), b512, 0, stream>>>(y1, WqkvT, bqkv, nullptr, qkvb, 4096, 3072, 1024);
  prep_kv<<<dim3(64, 16), b256, 0, stream>>>(qkvb, Kp, Vp);
  attn_kernel<<<dim3(32, 16), b256, 0, stream>>>(qkvb, Kp, Vp, ctxb);
  // Wo: M=4096 N=1024 K=1024; (4096/128)*(1024/64) = 32*16 = 512 blocks
  gemm4w<true, false><<<dim3(512), b256, 0, stream>>>(ctxb, WoT, bo, x, x1, 4096, 1024, 1024);
  ln_kernel<<<4096, b256, 0, stream>>>(x1, g2, be2, y1);
  // W1: M=4096 N=4096 K=1024; 16*16 = 256 blocks
  gemm8<true, false, true, false><<<dim3(256), b512, 0, stream>>>(y1, W1T, b1, nullptr, hbuf, 4096, 4096, 1024);
  // W2: M=4096 N=1024 K=4096; 32*16 = 512 blocks
  gemm4w<true, false><<<dim3(512), b256, 0, stream>>>(hbuf, W2T, b2, x1, out, 4096, 1024, 4096);
}